// Round 10
// baseline (320.348 us; speedup 1.0000x reference)
//
#include <hip/hip_runtime.h>

// Problem constants
#define BATCH 2
#define SLEN 2048
#define DMODEL 1024
#define NHEAD 16
#define HDIM 64
#define MROWS (BATCH * SLEN)   // 4096

typedef __attribute__((ext_vector_type(8))) short bf16x8;
typedef __attribute__((ext_vector_type(4))) short bf16x4;
typedef __attribute__((ext_vector_type(4))) float f32x4;
typedef __attribute__((ext_vector_type(8))) _Float16 f16x8;
typedef __attribute__((ext_vector_type(4))) _Float16 f16x4;

__device__ inline short f2bf(float x) {
    union { float f; unsigned u; } v; v.f = x;
    unsigned r = (v.u + 0x7FFFu + ((v.u >> 16) & 1u)) >> 16;
    return (short)r;
}
__device__ inline float bf2f(short h) {
    union { unsigned u; float f; } v; v.u = ((unsigned)(unsigned short)h) << 16;
    return v.f;
}
__device__ inline unsigned fbits(float x) {
    union { float f; unsigned u; } v; v.f = x; return v.u;
}

// ---------------- prep: cast fp32 -> fp16
__global__ __launch_bounds__(256) void cast_f16(
    const float* __restrict__ in, _Float16* __restrict__ out, int n4)
{
    int i = blockIdx.x * 256 + threadIdx.x;
    if (i >= n4) return;
    float4 f = ((const float4*)in)[i];
    f16x4 h;
    h[0] = (_Float16)f.x; h[1] = (_Float16)f.y;
    h[2] = (_Float16)f.z; h[3] = (_Float16)f.w;
    ((f16x4*)out)[i] = h;
}

// ---------------- prep: transpose W[K][N] -> WT fp16 [N][K]
__global__ __launch_bounds__(256) void transpose_f16(
    const float* __restrict__ in, _Float16* __restrict__ outT, int K, int N)
{
    __shared__ float T[64][68];
    const int tid = threadIdx.x;
    const int n0 = blockIdx.x * 64, k0 = blockIdx.y * 64;
#pragma unroll
    for (int i = 0; i < 4; i++) {
        int idx = tid + i * 256;
        int r = idx >> 4, c4 = idx & 15;
        *(float4*)&T[r][c4 * 4] = *(const float4*)&in[(size_t)(k0 + r) * N + n0 + c4 * 4];
    }
    __syncthreads();
#pragma unroll
    for (int i = 0; i < 4; i++) {
        int idx = tid + i * 256;
        int n = idx >> 4, kg = idx & 15;
        f16x4 h;
#pragma unroll
        for (int j = 0; j < 4; j++)
            h[j] = (_Float16)T[kg * 4 + j][n];
        *(f16x4*)&outT[(size_t)(n0 + n) * K + k0 + kg * 4] = h;
    }
}

// ---------------- transpose V section of qkv -> vT[b][h][d][s]  (bf16)
__global__ __launch_bounds__(256) void transpose_v(
    const short* __restrict__ qkv, short* __restrict__ vT)
{
    __shared__ short T[64 * 68];   // [s][d], stride 68 shorts
    const int tid = threadIdx.x;
    const int bid = blockIdx.x;
    const int st = bid & 31, h = (bid >> 5) & 15, b = bid >> 9;
    const int s0 = st * 64;
    const short* src = qkv + (size_t)b * SLEN * (3 * DMODEL) + 2 * DMODEL + h * HDIM;

    const int srow = tid >> 3, sc8 = tid & 7;
#pragma unroll
    for (int it = 0; it < 2; it++) {
        int s = srow + it * 32;
        *(bf16x8*)&T[s * 68 + sc8 * 8] =
            *(const bf16x8*)&src[(size_t)(s0 + s) * (3 * DMODEL) + sc8 * 8];
    }
    __syncthreads();

    const int d = tid >> 2, sq = tid & 3;
    short* dst = vT + ((size_t)(b * NHEAD + h) * HDIM + d) * SLEN + s0 + sq * 16;
    bf16x8 o0, o1;
#pragma unroll
    for (int j = 0; j < 8; j++) {
        o0[j] = T[(sq * 16 + j) * 68 + d];
        o1[j] = T[(sq * 16 + 8 + j) * 68 + d];
    }
    *(bf16x8*)&dst[0] = o0;
    *(bf16x8*)&dst[8] = o1;
}

// ---------------- plain fp16 MFMA GEMM: C = A[M,K] · B[K,N] + bias
// B given TRANSPOSED [N][K] fp16. 128x128x32 tiles.
#define GSTR 40   // LDS row stride (f16 elems): 80 B, 16B-aligned, 2-way-free banks

template<int OUT_BF16>
__global__ __launch_bounds__(256) void gemm_f16(
    const _Float16* __restrict__ A, const _Float16* __restrict__ Bw,
    const float* __restrict__ bias, void* __restrict__ Cout,
    int M, int N, int K)
{
    __shared__ _Float16 As[128 * GSTR], Bs[128 * GSTR];

    const int tid  = threadIdx.x;
    const int wave = tid >> 6, lane = tid & 63;
    const int quad = lane >> 4, lr = lane & 15;
    const int wm = (wave >> 1) * 64, wn = (wave & 1) * 64;
    const int row0 = blockIdx.y * 128, col0 = blockIdx.x * 128;

    f32x4 acc[4][4];
#pragma unroll
    for (int i = 0; i < 4; i++)
#pragma unroll
        for (int j = 0; j < 4; j++) acc[i][j] = (f32x4){0.f, 0.f, 0.f, 0.f};

    const int sr = tid >> 2, sc = tid & 3;

    for (int k0 = 0; k0 < K; k0 += 32) {
        __syncthreads();
#pragma unroll
        for (int i = 0; i < 2; i++) {
            int rr = sr + i * 64;
            size_t ga = (size_t)(row0 + rr) * K + k0 + sc * 8;
            size_t gb = (size_t)(col0 + rr) * K + k0 + sc * 8;
            int ls = rr * GSTR + sc * 8;
            *(f16x8*)&As[ls] = *(const f16x8*)&A[ga];
            *(f16x8*)&Bs[ls] = *(const f16x8*)&Bw[gb];
        }
        __syncthreads();

        f16x8 af[4];
#pragma unroll
        for (int mt = 0; mt < 4; mt++)
            af[mt] = *(const f16x8*)&As[(wm + mt * 16 + lr) * GSTR + quad * 8];
#pragma unroll
        for (int nt = 0; nt < 4; nt++) {
            f16x8 b = *(const f16x8*)&Bs[(wn + nt * 16 + lr) * GSTR + quad * 8];
#pragma unroll
            for (int mt = 0; mt < 4; mt++)
                acc[mt][nt] = __builtin_amdgcn_mfma_f32_16x16x32_f16(af[mt], b, acc[mt][nt], 0, 0, 0);
        }
    }

    // epilogue: D[m = quad*4 + r][n = lr]
#pragma unroll
    for (int mt = 0; mt < 4; mt++) {
#pragma unroll
        for (int nt = 0; nt < 4; nt++) {
            int col = col0 + wn + nt * 16 + lr;
            float bv = bias[col];
#pragma unroll
            for (int r = 0; r < 4; r++) {
                int row = row0 + wm + mt * 16 + quad * 4 + r;
                float v = acc[mt][nt][r] + bv;
                if (OUT_BF16)
                    ((short*)Cout)[(size_t)row * N + col] = f2bf(v);
                else
                    ((float*)Cout)[(size_t)row * N + col] = v;
            }
        }
    }
}

// ---------------- fused attention v6: QK^T via 16x16x32 (b128 K-frags),
// PV via 16x16x16 layout-chaining, pre-transposed V, stride-76 LDS,
// pointer-bumped prefetch, fp16 output.
#define ASTR 76   // LDS row stride (shorts): 2-way max bank aliasing
#define NT   (SLEN / 64)
#define QK_SCALE_LOG2E 0.1803368801111244f   // 0.125 * log2(e)

__global__ __launch_bounds__(256) void attn_mfma(
    const short* __restrict__ qkv, const short* __restrict__ vT,
    _Float16* __restrict__ attn)
{
    __shared__ short Ks[2][64 * ASTR];   // K tile, row-major [k][d]
    __shared__ short Vt[2][64 * ASTR];   // V^T tile [d][k]

    const int tid  = threadIdx.x;
    const int lane = tid & 63;
    const int wave = tid >> 6;
    const int quad = lane >> 4;
    const int lr   = lane & 15;
    const int wq0  = wave * 16;

    const int bid = blockIdx.x;
    const int qt = bid & 31;
    const int h  = (bid >> 5) & 15;
    const int b  = bid >> 9;
    const int q0 = qt * 64;

    const short* qbase = qkv + (size_t)b * SLEN * (3 * DMODEL) + h * HDIM;
    const short* kbase = qbase + DMODEL;
    const short* vtbase = vT + (size_t)(b * NHEAD + h) * HDIM * SLEN;

    // Q as 16x16x32 B-frags, pre-scaled: qf[c][j] = Q[q=lr][d=c*32+quad*8+j]
    bf16x8 qf[2];
#pragma unroll
    for (int c = 0; c < 2; c++) {
        bf16x8 q = *(const bf16x8*)&qbase[(size_t)(q0 + wq0 + lr) * (3 * DMODEL) + c * 32 + quad * 8];
#pragma unroll
        for (int j = 0; j < 8; j++)
            q[j] = f2bf(bf2f(q[j]) * QK_SCALE_LOG2E);
        qf[c] = q;
    }

    // ones A-fragment for the row-sum MFMA (16x16x16)
    bf16x4 ones;
#pragma unroll
    for (int j = 0; j < 4; j++) ones[j] = (short)0x3F80;

    f32x4 oacc[4];   // O^T tiles: D[d = dt*16 + quad*4 + r][q = lr]
#pragma unroll
    for (int t = 0; t < 4; t++) oacc[t] = (f32x4){0.f, 0.f, 0.f, 0.f};
    f32x4 sacc = {0.f, 0.f, 0.f, 0.f};

    const int srow = tid >> 3, sc8 = tid & 7;

    // pointer-bumped staging addresses
    const short* kp0 = kbase + (size_t)srow * (3 * DMODEL) + sc8 * 8;
    const short* kp1 = kp0 + 32 * (3 * DMODEL);
    const short* vp0 = vtbase + (size_t)srow * SLEN + sc8 * 8;
    const short* vp1 = vp0 + 32 * SLEN;

    bf16x8 kpre[2], vpre[2];
    kpre[0] = *(const bf16x8*)kp0; kpre[1] = *(const bf16x8*)kp1;
    vpre[0] = *(const bf16x8*)vp0; vpre[1] = *(const bf16x8*)vp1;
    kp0 += 64 * (3 * DMODEL); kp1 += 64 * (3 * DMODEL);
    vp0 += 64; vp1 += 64;

    for (int kt = 0; kt < NT; kt++) {
        const int cur = kt & 1;
        short* ks = Ks[cur];
        short* vt = Vt[cur];

        // write tile kt (in regs) to LDS buffer `cur`
        *(bf16x8*)&ks[srow * ASTR + sc8 * 8] = kpre[0];
        *(bf16x8*)&ks[(srow + 32) * ASTR + sc8 * 8] = kpre[1];
        *(bf16x8*)&vt[srow * ASTR + sc8 * 8] = vpre[0];
        *(bf16x8*)&vt[(srow + 32) * ASTR + sc8 * 8] = vpre[1];

        // issue global loads for tile kt+1
        if (kt + 1 < NT) {
            kpre[0] = *(const bf16x8*)kp0; kpre[1] = *(const bf16x8*)kp1;
            vpre[0] = *(const bf16x8*)vp0; vpre[1] = *(const bf16x8*)vp1;
            kp0 += 64 * (3 * DMODEL); kp1 += 64 * (3 * DMODEL);
            vp0 += 64; vp1 += 64;
        }

        __syncthreads();   // buffer `cur` complete; reads of 1-cur done pre-barrier

        // per 16-key tile: S^T = K·Q^T (16x16x32), exp2, O^T += V^T·P^T (16x16x16)
#pragma unroll
        for (int ct = 0; ct < 4; ct++) {
            bf16x8 kf0 = *(const bf16x8*)&ks[(ct * 16 + lr) * ASTR + quad * 8];
            bf16x8 kf1 = *(const bf16x8*)&ks[(ct * 16 + lr) * ASTR + 32 + quad * 8];
            f32x4 st = {0.f, 0.f, 0.f, 0.f};
            st = __builtin_amdgcn_mfma_f32_16x16x32_bf16(kf0, qf[0], st, 0, 0, 0);
            st = __builtin_amdgcn_mfma_f32_16x16x32_bf16(kf1, qf[1], st, 0, 0, 0);
            float p[4];
#pragma unroll
            for (int r = 0; r < 4; r++) p[r] = exp2f(st[r]);
            union { uint2 u; bf16x4 v; } pk;
            pk.u.x = __builtin_amdgcn_perm(fbits(p[1]), fbits(p[0]), 0x07060302u);
            pk.u.y = __builtin_amdgcn_perm(fbits(p[3]), fbits(p[2]), 0x07060302u);
            bf16x4 pf = pk.v;
            sacc = __builtin_amdgcn_mfma_f32_16x16x16bf16_1k(ones, pf, sacc, 0, 0, 0);
#pragma unroll
            for (int dt = 0; dt < 4; dt++) {
                bf16x4 vf = *(const bf16x4*)&vt[(dt * 16 + lr) * ASTR + ct * 16 + quad * 4];
                oacc[dt] = __builtin_amdgcn_mfma_f32_16x16x16bf16_1k(vf, pf, oacc[dt], 0, 0, 0);
            }
        }
    }

    const float inv = 1.0f / sacc[0];

    // write O as plain fp16 for the proj GEMM
    const int row = b * SLEN + q0 + wq0 + lr;
#pragma unroll
    for (int dt = 0; dt < 4; dt++) {
        f16x4 h4;
#pragma unroll
        for (int r = 0; r < 4; r++)
            h4[r] = (_Float16)(oacc[dt][r] * inv);
        int col = h * HDIM + dt * 16 + quad * 4;
        *(f16x4*)&attn[(size_t)row * DMODEL + col] = h4;
    }
}

extern "C" void kernel_launch(void* const* d_in, const int* in_sizes, int n_in,
                              void* d_out, int out_size, void* d_ws, size_t ws_size,
                              hipStream_t stream) {
    (void)in_sizes; (void)n_in; (void)out_size; (void)ws_size;
    const float* x     = (const float*)d_in[0];
    const float* Wqkv  = (const float*)d_in[1];
    const float* bqkv  = (const float*)d_in[2];
    const float* Wproj = (const float*)d_in[3];
    const float* bproj = (const float*)d_in[4];
    float* out = (float*)d_out;

    // workspace layout (2-byte units), peak ~58.6 MB
    short* qkv = (short*)d_ws;                               // 4096*3072 bf16
    _Float16* xf = (_Float16*)(qkv + (size_t)MROWS * 3 * DMODEL);  // 4096*1024 f16
    _Float16* wq = xf + (size_t)MROWS * DMODEL;              // 3072*1024 f16 (W_qkv^T)
    _Float16* wp = wq + (size_t)3 * DMODEL * DMODEL;         // 1024*1024 f16 (W_proj^T)
    short* vT = (short*)(wp + (size_t)DMODEL * DMODEL);      // 4096*1024 bf16
    _Float16* attnb = (_Float16*)(vT + (size_t)MROWS * DMODEL); // 4096*1024 f16

    // prep: cast x to fp16; transpose weights to fp16
    cast_f16<<<dim3(MROWS * DMODEL / 4 / 256), 256, 0, stream>>>(x, xf, MROWS * DMODEL / 4);
    transpose_f16<<<dim3(3 * DMODEL / 64, DMODEL / 64), 256, 0, stream>>>(Wqkv, wq, DMODEL, 3 * DMODEL);
    transpose_f16<<<dim3(DMODEL / 64, DMODEL / 64), 256, 0, stream>>>(Wproj, wp, DMODEL, DMODEL);

    // 1) qkv(bf16) = x @ W_qkv + b_qkv   (plain fp16 MFMA)
    gemm_f16<1><<<dim3(3 * DMODEL / 128, MROWS / 128), 256, 0, stream>>>(
        xf, wq, bqkv, (void*)qkv, MROWS, 3 * DMODEL, DMODEL);

    // 1b) transpose V section -> vT[b][h][d][s]
    transpose_v<<<dim3(BATCH * NHEAD * (SLEN / 64)), 256, 0, stream>>>(qkv, vT);

    // 2) fused attention: bf16 qkv + vT -> attn (fp16)
    attn_mfma<<<dim3(BATCH * NHEAD * (SLEN / 64)), 256, 0, stream>>>(qkv, vT, attnb);

    // 3) out(fp32) = attn @ W_proj + b_proj   (plain fp16 MFMA)
    gemm_f16<0><<<dim3(DMODEL / 128, MROWS / 128), 256, 0, stream>>>(
        attnb, wp, bproj, (void*)out, MROWS, DMODEL, DMODEL);
}

// Round 11
// 230.005 us; speedup vs baseline: 1.3928x; 1.3928x over previous
//
#include <hip/hip_runtime.h>

// Problem constants
#define BATCH 2
#define SLEN 2048
#define DMODEL 1024
#define NHEAD 16
#define HDIM 64
#define MROWS (BATCH * SLEN)   // 4096

typedef __attribute__((ext_vector_type(8))) short bf16x8;
typedef __attribute__((ext_vector_type(4))) short bf16x4;
typedef __attribute__((ext_vector_type(4))) float f32x4;
typedef __attribute__((ext_vector_type(8))) _Float16 f16x8;
typedef __attribute__((ext_vector_type(4))) _Float16 f16x4;

__device__ inline short f2bf(float x) {
    union { float f; unsigned u; } v; v.f = x;
    unsigned r = (v.u + 0x7FFFu + ((v.u >> 16) & 1u)) >> 16;
    return (short)r;
}
__device__ inline float bf2f(short h) {
    union { unsigned u; float f; } v; v.u = ((unsigned)(unsigned short)h) << 16;
    return v.f;
}
__device__ inline unsigned fbits(float x) {
    union { float f; unsigned u; } v; v.f = x; return v.u;
}

// ---------------- prep: cast fp32 -> fp16
__global__ __launch_bounds__(256) void cast_f16(
    const float* __restrict__ in, _Float16* __restrict__ out, int n4)
{
    int i = blockIdx.x * 256 + threadIdx.x;
    if (i >= n4) return;
    float4 f = ((const float4*)in)[i];
    f16x4 h;
    h[0] = (_Float16)f.x; h[1] = (_Float16)f.y;
    h[2] = (_Float16)f.z; h[3] = (_Float16)f.w;
    ((f16x4*)out)[i] = h;
}

// ---------------- prep: transpose W[K][N] -> WT fp16 [N][K]
__global__ __launch_bounds__(256) void transpose_f16(
    const float* __restrict__ in, _Float16* __restrict__ outT, int K, int N)
{
    __shared__ float T[64][68];
    const int tid = threadIdx.x;
    const int n0 = blockIdx.x * 64, k0 = blockIdx.y * 64;
#pragma unroll
    for (int i = 0; i < 4; i++) {
        int idx = tid + i * 256;
        int r = idx >> 4, c4 = idx & 15;
        *(float4*)&T[r][c4 * 4] = *(const float4*)&in[(size_t)(k0 + r) * N + n0 + c4 * 4];
    }
    __syncthreads();
#pragma unroll
    for (int i = 0; i < 4; i++) {
        int idx = tid + i * 256;
        int n = idx >> 4, kg = idx & 15;
        f16x4 h;
#pragma unroll
        for (int j = 0; j < 4; j++)
            h[j] = (_Float16)T[kg * 4 + j][n];
        *(f16x4*)&outT[(size_t)(n0 + n) * K + k0 + kg * 4] = h;
    }
}

// ---------------- transpose V section of qkv -> vT[b][h][d][s]  (bf16)
__global__ __launch_bounds__(256) void transpose_v(
    const short* __restrict__ qkv, short* __restrict__ vT)
{
    __shared__ short T[64 * 68];   // [s][d], stride 68 shorts
    const int tid = threadIdx.x;
    const int bid = blockIdx.x;
    const int st = bid & 31, h = (bid >> 5) & 15, b = bid >> 9;
    const int s0 = st * 64;
    const short* src = qkv + (size_t)b * SLEN * (3 * DMODEL) + 2 * DMODEL + h * HDIM;

    const int srow = tid >> 3, sc8 = tid & 7;
#pragma unroll
    for (int it = 0; it < 2; it++) {
        int s = srow + it * 32;
        *(bf16x8*)&T[s * 68 + sc8 * 8] =
            *(const bf16x8*)&src[(size_t)(s0 + s) * (3 * DMODEL) + sc8 * 8];
    }
    __syncthreads();

    const int d = tid >> 2, sq = tid & 3;
    short* dst = vT + ((size_t)(b * NHEAD + h) * HDIM + d) * SLEN + s0 + sq * 16;
    bf16x8 o0, o1;
#pragma unroll
    for (int j = 0; j < 8; j++) {
        o0[j] = T[(sq * 16 + j) * 68 + d];
        o1[j] = T[(sq * 16 + 8 + j) * 68 + d];
    }
    *(bf16x8*)&dst[0] = o0;
    *(bf16x8*)&dst[8] = o1;
}

// ---------------- plain fp16 MFMA GEMM: C = A[M,K] · B[K,N] + bias
// B given TRANSPOSED [N][K] fp16. 128x128x32 tiles.
#define GSTR 40   // LDS row stride (f16 elems): 80 B, 16B-aligned, 2-way-free banks

template<int OUT_BF16>
__global__ __launch_bounds__(256) void gemm_f16(
    const _Float16* __restrict__ A, const _Float16* __restrict__ Bw,
    const float* __restrict__ bias, void* __restrict__ Cout,
    int M, int N, int K)
{
    __shared__ _Float16 As[128 * GSTR], Bs[128 * GSTR];

    const int tid  = threadIdx.x;
    const int wave = tid >> 6, lane = tid & 63;
    const int quad = lane >> 4, lr = lane & 15;
    const int wm = (wave >> 1) * 64, wn = (wave & 1) * 64;
    const int row0 = blockIdx.y * 128, col0 = blockIdx.x * 128;

    f32x4 acc[4][4];
#pragma unroll
    for (int i = 0; i < 4; i++)
#pragma unroll
        for (int j = 0; j < 4; j++) acc[i][j] = (f32x4){0.f, 0.f, 0.f, 0.f};

    const int sr = tid >> 2, sc = tid & 3;

    for (int k0 = 0; k0 < K; k0 += 32) {
        __syncthreads();
#pragma unroll
        for (int i = 0; i < 2; i++) {
            int rr = sr + i * 64;
            size_t ga = (size_t)(row0 + rr) * K + k0 + sc * 8;
            size_t gb = (size_t)(col0 + rr) * K + k0 + sc * 8;
            int ls = rr * GSTR + sc * 8;
            *(f16x8*)&As[ls] = *(const f16x8*)&A[ga];
            *(f16x8*)&Bs[ls] = *(const f16x8*)&Bw[gb];
        }
        __syncthreads();

        f16x8 af[4];
#pragma unroll
        for (int mt = 0; mt < 4; mt++)
            af[mt] = *(const f16x8*)&As[(wm + mt * 16 + lr) * GSTR + quad * 8];
#pragma unroll
        for (int nt = 0; nt < 4; nt++) {
            f16x8 b = *(const f16x8*)&Bs[(wn + nt * 16 + lr) * GSTR + quad * 8];
#pragma unroll
            for (int mt = 0; mt < 4; mt++)
                acc[mt][nt] = __builtin_amdgcn_mfma_f32_16x16x32_f16(af[mt], b, acc[mt][nt], 0, 0, 0);
        }
    }

    // epilogue: D[m = quad*4 + r][n = lr]
#pragma unroll
    for (int mt = 0; mt < 4; mt++) {
#pragma unroll
        for (int nt = 0; nt < 4; nt++) {
            int col = col0 + wn + nt * 16 + lr;
            float bv = bias[col];
#pragma unroll
            for (int r = 0; r < 4; r++) {
                int row = row0 + wm + mt * 16 + quad * 4 + r;
                float v = acc[mt][nt][r] + bv;
                if (OUT_BF16)
                    ((short*)Cout)[(size_t)row * N + col] = f2bf(v);
                else
                    ((float*)Cout)[(size_t)row * N + col] = v;
            }
        }
    }
}

// ---------------- fused attention v7: 16x16x16 layout-chaining (all LDS
// reads b64-aligned), wave owns 32 q-rows (K/V frag reads shared across two
// q-subtiles), block = 128 q-rows, grid 512. Double-buffered LDS, 1 barrier.
#define ASTR 76   // LDS row stride (shorts): 0 conflicts measured (r9)
#define NT   (SLEN / 64)
#define QK_SCALE_LOG2E 0.1803368801111244f   // 0.125 * log2(e)

__global__ __launch_bounds__(256) void attn_mfma(
    const short* __restrict__ qkv, const short* __restrict__ vT,
    _Float16* __restrict__ attn)
{
    __shared__ short Ks[2][64 * ASTR];   // K tile, row-major [k][d]
    __shared__ short Vt[2][64 * ASTR];   // V^T tile [d][k]

    const int tid  = threadIdx.x;
    const int lane = tid & 63;
    const int wave = tid >> 6;
    const int quad = lane >> 4;
    const int lr   = lane & 15;
    const int wq0  = wave * 32;

    const int bid = blockIdx.x;
    const int qt = bid & 15;           // 16 q-tiles of 128
    const int h  = (bid >> 4) & 15;
    const int b  = bid >> 8;
    const int q0 = qt * 128;

    const short* qbase = qkv + (size_t)b * SLEN * (3 * DMODEL) + h * HDIM;
    const short* kbase = qbase + DMODEL;
    const short* vtbase = vT + (size_t)(b * NHEAD + h) * HDIM * SLEN;

    // Q as 16x16x16 B-frags, pre-scaled: qf[qs][ds][j] = Q[q=qs*16+lr][d=ds*16+quad*4+j]
    bf16x4 qf[2][4];
#pragma unroll
    for (int qs = 0; qs < 2; qs++)
#pragma unroll
        for (int ds = 0; ds < 4; ds++) {
            bf16x4 q = *(const bf16x4*)&qbase[(size_t)(q0 + wq0 + qs * 16 + lr) * (3 * DMODEL) + ds * 16 + quad * 4];
#pragma unroll
            for (int j = 0; j < 4; j++)
                q[j] = f2bf(bf2f(q[j]) * QK_SCALE_LOG2E);
            qf[qs][ds] = q;
        }

    // ones A-fragment for the row-sum MFMA
    bf16x4 ones;
#pragma unroll
    for (int j = 0; j < 4; j++) ones[j] = (short)0x3F80;

    f32x4 oacc[2][4];   // O^T tiles per q-subtile: D[d = dt*16+quad*4+r][q = lr]
#pragma unroll
    for (int qs = 0; qs < 2; qs++)
#pragma unroll
        for (int t = 0; t < 4; t++) oacc[qs][t] = (f32x4){0.f, 0.f, 0.f, 0.f};
    f32x4 sacc[2] = {{0.f, 0.f, 0.f, 0.f}, {0.f, 0.f, 0.f, 0.f}};

    const int srow = tid >> 3, sc8 = tid & 7;

    // pointer-bumped staging addresses
    const short* kp0 = kbase + (size_t)srow * (3 * DMODEL) + sc8 * 8;
    const short* kp1 = kp0 + 32 * (3 * DMODEL);
    const short* vp0 = vtbase + (size_t)srow * SLEN + sc8 * 8;
    const short* vp1 = vp0 + 32 * SLEN;

    bf16x8 kpre[2], vpre[2];
    kpre[0] = *(const bf16x8*)kp0; kpre[1] = *(const bf16x8*)kp1;
    vpre[0] = *(const bf16x8*)vp0; vpre[1] = *(const bf16x8*)vp1;
    kp0 += 64 * (3 * DMODEL); kp1 += 64 * (3 * DMODEL);
    vp0 += 64; vp1 += 64;

    for (int kt = 0; kt < NT; kt++) {
        const int cur = kt & 1;
        short* ks = Ks[cur];
        short* vt = Vt[cur];

        // write tile kt (in regs) to LDS buffer `cur`
        *(bf16x8*)&ks[srow * ASTR + sc8 * 8] = kpre[0];
        *(bf16x8*)&ks[(srow + 32) * ASTR + sc8 * 8] = kpre[1];
        *(bf16x8*)&vt[srow * ASTR + sc8 * 8] = vpre[0];
        *(bf16x8*)&vt[(srow + 32) * ASTR + sc8 * 8] = vpre[1];

        // issue global loads for tile kt+1
        if (kt + 1 < NT) {
            kpre[0] = *(const bf16x8*)kp0; kpre[1] = *(const bf16x8*)kp1;
            vpre[0] = *(const bf16x8*)vp0; vpre[1] = *(const bf16x8*)vp1;
            kp0 += 64 * (3 * DMODEL); kp1 += 64 * (3 * DMODEL);
            vp0 += 64; vp1 += 64;
        }

        __syncthreads();   // buffer `cur` complete; reads of 1-cur done pre-barrier

        // per 16-key tile: S^T = K·Q^T (shared kf), exp2, O^T += V^T·P^T (shared vf)
#pragma unroll
        for (int ct = 0; ct < 4; ct++) {
            bf16x4 kf[4];
#pragma unroll
            for (int ds = 0; ds < 4; ds++)
                kf[ds] = *(const bf16x4*)&ks[(ct * 16 + lr) * ASTR + ds * 16 + quad * 4];

            f32x4 st0 = {0.f, 0.f, 0.f, 0.f}, st1 = {0.f, 0.f, 0.f, 0.f};
#pragma unroll
            for (int ds = 0; ds < 4; ds++) {
                st0 = __builtin_amdgcn_mfma_f32_16x16x16bf16_1k(kf[ds], qf[0][ds], st0, 0, 0, 0);
                st1 = __builtin_amdgcn_mfma_f32_16x16x16bf16_1k(kf[ds], qf[1][ds], st1, 0, 0, 0);
            }

            float p0[4], p1[4];
#pragma unroll
            for (int r = 0; r < 4; r++) { p0[r] = exp2f(st0[r]); p1[r] = exp2f(st1[r]); }
            union { uint2 u; bf16x4 v; } pk0, pk1;
            pk0.u.x = __builtin_amdgcn_perm(fbits(p0[1]), fbits(p0[0]), 0x07060302u);
            pk0.u.y = __builtin_amdgcn_perm(fbits(p0[3]), fbits(p0[2]), 0x07060302u);
            pk1.u.x = __builtin_amdgcn_perm(fbits(p1[1]), fbits(p1[0]), 0x07060302u);
            pk1.u.y = __builtin_amdgcn_perm(fbits(p1[3]), fbits(p1[2]), 0x07060302u);
            bf16x4 pf0 = pk0.v, pf1 = pk1.v;

            sacc[0] = __builtin_amdgcn_mfma_f32_16x16x16bf16_1k(ones, pf0, sacc[0], 0, 0, 0);
            sacc[1] = __builtin_amdgcn_mfma_f32_16x16x16bf16_1k(ones, pf1, sacc[1], 0, 0, 0);
#pragma unroll
            for (int dt = 0; dt < 4; dt++) {
                bf16x4 vf = *(const bf16x4*)&vt[(dt * 16 + lr) * ASTR + ct * 16 + quad * 4];
                oacc[0][dt] = __builtin_amdgcn_mfma_f32_16x16x16bf16_1k(vf, pf0, oacc[0][dt], 0, 0, 0);
                oacc[1][dt] = __builtin_amdgcn_mfma_f32_16x16x16bf16_1k(vf, pf1, oacc[1][dt], 0, 0, 0);
            }
        }
    }

    // write O as plain fp16 for the proj GEMM
#pragma unroll
    for (int qs = 0; qs < 2; qs++) {
        const float inv = 1.0f / sacc[qs][0];
        const int row = b * SLEN + q0 + wq0 + qs * 16 + lr;
#pragma unroll
        for (int dt = 0; dt < 4; dt++) {
            f16x4 h4;
#pragma unroll
            for (int r = 0; r < 4; r++)
                h4[r] = (_Float16)(oacc[qs][dt][r] * inv);
            int col = h * HDIM + dt * 16 + quad * 4;
            *(f16x4*)&attn[(size_t)row * DMODEL + col] = h4;
        }
    }
}

extern "C" void kernel_launch(void* const* d_in, const int* in_sizes, int n_in,
                              void* d_out, int out_size, void* d_ws, size_t ws_size,
                              hipStream_t stream) {
    (void)in_sizes; (void)n_in; (void)out_size; (void)ws_size;
    const float* x     = (const float*)d_in[0];
    const float* Wqkv  = (const float*)d_in[1];
    const float* bqkv  = (const float*)d_in[2];
    const float* Wproj = (const float*)d_in[3];
    const float* bproj = (const float*)d_in[4];
    float* out = (float*)d_out;

    // workspace layout (2-byte units), peak ~58.6 MB
    short* qkv = (short*)d_ws;                               // 4096*3072 bf16
    _Float16* xf = (_Float16*)(qkv + (size_t)MROWS * 3 * DMODEL);  // 4096*1024 f16
    _Float16* wq = xf + (size_t)MROWS * DMODEL;              // 3072*1024 f16 (W_qkv^T)
    _Float16* wp = wq + (size_t)3 * DMODEL * DMODEL;         // 1024*1024 f16 (W_proj^T)
    short* vT = (short*)(wp + (size_t)DMODEL * DMODEL);      // 4096*1024 bf16
    _Float16* attnb = (_Float16*)(vT + (size_t)MROWS * DMODEL); // 4096*1024 f16

    // prep: cast x to fp16; transpose weights to fp16
    cast_f16<<<dim3(MROWS * DMODEL / 4 / 256), 256, 0, stream>>>(x, xf, MROWS * DMODEL / 4);
    transpose_f16<<<dim3(3 * DMODEL / 64, DMODEL / 64), 256, 0, stream>>>(Wqkv, wq, DMODEL, 3 * DMODEL);
    transpose_f16<<<dim3(DMODEL / 64, DMODEL / 64), 256, 0, stream>>>(Wproj, wp, DMODEL, DMODEL);

    // 1) qkv(bf16) = x @ W_qkv + b_qkv   (plain fp16 MFMA)
    gemm_f16<1><<<dim3(3 * DMODEL / 128, MROWS / 128), 256, 0, stream>>>(
        xf, wq, bqkv, (void*)qkv, MROWS, 3 * DMODEL, DMODEL);

    // 1b) transpose V section -> vT[b][h][d][s]
    transpose_v<<<dim3(BATCH * NHEAD * (SLEN / 64)), 256, 0, stream>>>(qkv, vT);

    // 2) fused attention: bf16 qkv + vT -> attn (fp16); 128 q-rows/block
    attn_mfma<<<dim3(BATCH * NHEAD * (SLEN / 128)), 256, 0, stream>>>(qkv, vT, attnb);

    // 3) out(fp32) = attn @ W_proj + b_proj   (plain fp16 MFMA)
    gemm_f16<0><<<dim3(DMODEL / 128, MROWS / 128), 256, 0, stream>>>(
        attnb, wp, bproj, (void*)out, MROWS, DMODEL, DMODEL);
}

// Round 12
// 221.922 us; speedup vs baseline: 1.4435x; 1.0364x over previous
//
#include <hip/hip_runtime.h>

// Problem constants
#define BATCH 2
#define SLEN 2048
#define DMODEL 1024
#define NHEAD 16
#define HDIM 64
#define MROWS (BATCH * SLEN)   // 4096

typedef __attribute__((ext_vector_type(8))) short bf16x8;
typedef __attribute__((ext_vector_type(4))) short bf16x4;
typedef __attribute__((ext_vector_type(4))) float f32x4;
typedef __attribute__((ext_vector_type(8))) _Float16 f16x8;
typedef __attribute__((ext_vector_type(4))) _Float16 f16x4;

__device__ inline short f2bf(float x) {
    union { float f; unsigned u; } v; v.f = x;
    unsigned r = (v.u + 0x7FFFu + ((v.u >> 16) & 1u)) >> 16;
    return (short)r;
}
__device__ inline float bf2f(short h) {
    union { unsigned u; float f; } v; v.u = ((unsigned)(unsigned short)h) << 16;
    return v.f;
}
__device__ inline unsigned fbits(float x) {
    union { float f; unsigned u; } v; v.f = x; return v.u;
}
// raw hardware exp2: one v_exp_f32 (args bounded; no denormal fixup needed)
__device__ inline float hw_exp2(float x) {
#if __has_builtin(__builtin_amdgcn_exp2f)
    return __builtin_amdgcn_exp2f(x);
#else
    float r;
    asm("v_exp_f32 %0, %1" : "=v"(r) : "v"(x));
    return r;
#endif
}

// ---------------- prep: cast fp32 -> fp16
__global__ __launch_bounds__(256) void cast_f16(
    const float* __restrict__ in, _Float16* __restrict__ out, int n4)
{
    int i = blockIdx.x * 256 + threadIdx.x;
    if (i >= n4) return;
    float4 f = ((const float4*)in)[i];
    f16x4 h;
    h[0] = (_Float16)f.x; h[1] = (_Float16)f.y;
    h[2] = (_Float16)f.z; h[3] = (_Float16)f.w;
    ((f16x4*)out)[i] = h;
}

// ---------------- prep: transpose W[K][N] -> WT fp16 [N][K]
__global__ __launch_bounds__(256) void transpose_f16(
    const float* __restrict__ in, _Float16* __restrict__ outT, int K, int N)
{
    __shared__ float T[64][68];
    const int tid = threadIdx.x;
    const int n0 = blockIdx.x * 64, k0 = blockIdx.y * 64;
#pragma unroll
    for (int i = 0; i < 4; i++) {
        int idx = tid + i * 256;
        int r = idx >> 4, c4 = idx & 15;
        *(float4*)&T[r][c4 * 4] = *(const float4*)&in[(size_t)(k0 + r) * N + n0 + c4 * 4];
    }
    __syncthreads();
#pragma unroll
    for (int i = 0; i < 4; i++) {
        int idx = tid + i * 256;
        int n = idx >> 4, kg = idx & 15;
        f16x4 h;
#pragma unroll
        for (int j = 0; j < 4; j++)
            h[j] = (_Float16)T[kg * 4 + j][n];
        *(f16x4*)&outT[(size_t)(n0 + n) * K + k0 + kg * 4] = h;
    }
}

// ---------------- transpose V section of qkv -> vT[b][h][d][s]  (bf16)
__global__ __launch_bounds__(256) void transpose_v(
    const short* __restrict__ qkv, short* __restrict__ vT)
{
    __shared__ short T[64 * 68];   // [s][d], stride 68 shorts
    const int tid = threadIdx.x;
    const int bid = blockIdx.x;
    const int st = bid & 31, h = (bid >> 5) & 15, b = bid >> 9;
    const int s0 = st * 64;
    const short* src = qkv + (size_t)b * SLEN * (3 * DMODEL) + 2 * DMODEL + h * HDIM;

    const int srow = tid >> 3, sc8 = tid & 7;
#pragma unroll
    for (int it = 0; it < 2; it++) {
        int s = srow + it * 32;
        *(bf16x8*)&T[s * 68 + sc8 * 8] =
            *(const bf16x8*)&src[(size_t)(s0 + s) * (3 * DMODEL) + sc8 * 8];
    }
    __syncthreads();

    const int d = tid >> 2, sq = tid & 3;
    short* dst = vT + ((size_t)(b * NHEAD + h) * HDIM + d) * SLEN + s0 + sq * 16;
    bf16x8 o0, o1;
#pragma unroll
    for (int j = 0; j < 8; j++) {
        o0[j] = T[(sq * 16 + j) * 68 + d];
        o1[j] = T[(sq * 16 + 8 + j) * 68 + d];
    }
    *(bf16x8*)&dst[0] = o0;
    *(bf16x8*)&dst[8] = o1;
}

// ---------------- plain fp16 MFMA GEMM: C = A[M,K] · B[K,N] + bias
// B given TRANSPOSED [N][K] fp16. 128x128x32 tiles.
#define GSTR 40   // LDS row stride (f16 elems): 80 B, 16B-aligned, 2-way-free banks

template<int OUT_BF16>
__global__ __launch_bounds__(256) void gemm_f16(
    const _Float16* __restrict__ A, const _Float16* __restrict__ Bw,
    const float* __restrict__ bias, void* __restrict__ Cout,
    int M, int N, int K)
{
    __shared__ _Float16 As[128 * GSTR], Bs[128 * GSTR];

    const int tid  = threadIdx.x;
    const int wave = tid >> 6, lane = tid & 63;
    const int quad = lane >> 4, lr = lane & 15;
    const int wm = (wave >> 1) * 64, wn = (wave & 1) * 64;
    const int row0 = blockIdx.y * 128, col0 = blockIdx.x * 128;

    f32x4 acc[4][4];
#pragma unroll
    for (int i = 0; i < 4; i++)
#pragma unroll
        for (int j = 0; j < 4; j++) acc[i][j] = (f32x4){0.f, 0.f, 0.f, 0.f};

    const int sr = tid >> 2, sc = tid & 3;

    for (int k0 = 0; k0 < K; k0 += 32) {
        __syncthreads();
#pragma unroll
        for (int i = 0; i < 2; i++) {
            int rr = sr + i * 64;
            size_t ga = (size_t)(row0 + rr) * K + k0 + sc * 8;
            size_t gb = (size_t)(col0 + rr) * K + k0 + sc * 8;
            int ls = rr * GSTR + sc * 8;
            *(f16x8*)&As[ls] = *(const f16x8*)&A[ga];
            *(f16x8*)&Bs[ls] = *(const f16x8*)&Bw[gb];
        }
        __syncthreads();

        f16x8 af[4];
#pragma unroll
        for (int mt = 0; mt < 4; mt++)
            af[mt] = *(const f16x8*)&As[(wm + mt * 16 + lr) * GSTR + quad * 8];
#pragma unroll
        for (int nt = 0; nt < 4; nt++) {
            f16x8 b = *(const f16x8*)&Bs[(wn + nt * 16 + lr) * GSTR + quad * 8];
#pragma unroll
            for (int mt = 0; mt < 4; mt++)
                acc[mt][nt] = __builtin_amdgcn_mfma_f32_16x16x32_f16(af[mt], b, acc[mt][nt], 0, 0, 0);
        }
    }

    // epilogue: D[m = quad*4 + r][n = lr]
#pragma unroll
    for (int mt = 0; mt < 4; mt++) {
#pragma unroll
        for (int nt = 0; nt < 4; nt++) {
            int col = col0 + wn + nt * 16 + lr;
            float bv = bias[col];
#pragma unroll
            for (int r = 0; r < 4; r++) {
                int row = row0 + wm + mt * 16 + quad * 4 + r;
                float v = acc[mt][nt][r] + bv;
                if (OUT_BF16)
                    ((short*)Cout)[(size_t)row * N + col] = f2bf(v);
                else
                    ((float*)Cout)[(size_t)row * N + col] = v;
            }
        }
    }
}

// ---------------- fused attention v8: v7 + raw v_exp_f32 (exp2f was lowering
// to the multi-instruction libm expansion without fast-math — 5x VALU).
#define ASTR 76   // LDS row stride (shorts): 0 conflicts measured (r9)
#define NT   (SLEN / 64)
#define QK_SCALE_LOG2E 0.1803368801111244f   // 0.125 * log2(e)

__global__ __launch_bounds__(256) void attn_mfma(
    const short* __restrict__ qkv, const short* __restrict__ vT,
    _Float16* __restrict__ attn)
{
    __shared__ short Ks[2][64 * ASTR];   // K tile, row-major [k][d]
    __shared__ short Vt[2][64 * ASTR];   // V^T tile [d][k]

    const int tid  = threadIdx.x;
    const int lane = tid & 63;
    const int wave = tid >> 6;
    const int quad = lane >> 4;
    const int lr   = lane & 15;
    const int wq0  = wave * 32;

    const int bid = blockIdx.x;
    const int qt = bid & 15;           // 16 q-tiles of 128
    const int h  = (bid >> 4) & 15;
    const int b  = bid >> 8;
    const int q0 = qt * 128;

    const short* qbase = qkv + (size_t)b * SLEN * (3 * DMODEL) + h * HDIM;
    const short* kbase = qbase + DMODEL;
    const short* vtbase = vT + (size_t)(b * NHEAD + h) * HDIM * SLEN;

    // Q as 16x16x16 B-frags, pre-scaled: qf[qs][ds][j] = Q[q=qs*16+lr][d=ds*16+quad*4+j]
    bf16x4 qf[2][4];
#pragma unroll
    for (int qs = 0; qs < 2; qs++)
#pragma unroll
        for (int ds = 0; ds < 4; ds++) {
            bf16x4 q = *(const bf16x4*)&qbase[(size_t)(q0 + wq0 + qs * 16 + lr) * (3 * DMODEL) + ds * 16 + quad * 4];
#pragma unroll
            for (int j = 0; j < 4; j++)
                q[j] = f2bf(bf2f(q[j]) * QK_SCALE_LOG2E);
            qf[qs][ds] = q;
        }

    // ones A-fragment for the row-sum MFMA
    bf16x4 ones;
#pragma unroll
    for (int j = 0; j < 4; j++) ones[j] = (short)0x3F80;

    f32x4 oacc[2][4];   // O^T tiles per q-subtile: D[d = dt*16+quad*4+r][q = lr]
#pragma unroll
    for (int qs = 0; qs < 2; qs++)
#pragma unroll
        for (int t = 0; t < 4; t++) oacc[qs][t] = (f32x4){0.f, 0.f, 0.f, 0.f};
    f32x4 sacc[2] = {{0.f, 0.f, 0.f, 0.f}, {0.f, 0.f, 0.f, 0.f}};

    const int srow = tid >> 3, sc8 = tid & 7;

    // pointer-bumped staging addresses
    const short* kp0 = kbase + (size_t)srow * (3 * DMODEL) + sc8 * 8;
    const short* kp1 = kp0 + 32 * (3 * DMODEL);
    const short* vp0 = vtbase + (size_t)srow * SLEN + sc8 * 8;
    const short* vp1 = vp0 + 32 * SLEN;

    bf16x8 kpre[2], vpre[2];
    kpre[0] = *(const bf16x8*)kp0; kpre[1] = *(const bf16x8*)kp1;
    vpre[0] = *(const bf16x8*)vp0; vpre[1] = *(const bf16x8*)vp1;
    kp0 += 64 * (3 * DMODEL); kp1 += 64 * (3 * DMODEL);
    vp0 += 64; vp1 += 64;

    for (int kt = 0; kt < NT; kt++) {
        const int cur = kt & 1;
        short* ks = Ks[cur];
        short* vt = Vt[cur];

        // write tile kt (in regs) to LDS buffer `cur`
        *(bf16x8*)&ks[srow * ASTR + sc8 * 8] = kpre[0];
        *(bf16x8*)&ks[(srow + 32) * ASTR + sc8 * 8] = kpre[1];
        *(bf16x8*)&vt[srow * ASTR + sc8 * 8] = vpre[0];
        *(bf16x8*)&vt[(srow + 32) * ASTR + sc8 * 8] = vpre[1];

        // issue global loads for tile kt+1
        if (kt + 1 < NT) {
            kpre[0] = *(const bf16x8*)kp0; kpre[1] = *(const bf16x8*)kp1;
            vpre[0] = *(const bf16x8*)vp0; vpre[1] = *(const bf16x8*)vp1;
            kp0 += 64 * (3 * DMODEL); kp1 += 64 * (3 * DMODEL);
            vp0 += 64; vp1 += 64;
        }

        __syncthreads();   // buffer `cur` complete; reads of 1-cur done pre-barrier

        // per 16-key tile: S^T = K·Q^T (shared kf), exp2, O^T += V^T·P^T (shared vf)
#pragma unroll
        for (int ct = 0; ct < 4; ct++) {
            bf16x4 kf[4];
#pragma unroll
            for (int ds = 0; ds < 4; ds++)
                kf[ds] = *(const bf16x4*)&ks[(ct * 16 + lr) * ASTR + ds * 16 + quad * 4];

            f32x4 st0 = {0.f, 0.f, 0.f, 0.f}, st1 = {0.f, 0.f, 0.f, 0.f};
#pragma unroll
            for (int ds = 0; ds < 4; ds++) {
                st0 = __builtin_amdgcn_mfma_f32_16x16x16bf16_1k(kf[ds], qf[0][ds], st0, 0, 0, 0);
                st1 = __builtin_amdgcn_mfma_f32_16x16x16bf16_1k(kf[ds], qf[1][ds], st1, 0, 0, 0);
            }

            float p0[4], p1[4];
#pragma unroll
            for (int r = 0; r < 4; r++) { p0[r] = hw_exp2(st0[r]); p1[r] = hw_exp2(st1[r]); }
            union { uint2 u; bf16x4 v; } pk0, pk1;
            pk0.u.x = __builtin_amdgcn_perm(fbits(p0[1]), fbits(p0[0]), 0x07060302u);
            pk0.u.y = __builtin_amdgcn_perm(fbits(p0[3]), fbits(p0[2]), 0x07060302u);
            pk1.u.x = __builtin_amdgcn_perm(fbits(p1[1]), fbits(p1[0]), 0x07060302u);
            pk1.u.y = __builtin_amdgcn_perm(fbits(p1[3]), fbits(p1[2]), 0x07060302u);
            bf16x4 pf0 = pk0.v, pf1 = pk1.v;

            sacc[0] = __builtin_amdgcn_mfma_f32_16x16x16bf16_1k(ones, pf0, sacc[0], 0, 0, 0);
            sacc[1] = __builtin_amdgcn_mfma_f32_16x16x16bf16_1k(ones, pf1, sacc[1], 0, 0, 0);
#pragma unroll
            for (int dt = 0; dt < 4; dt++) {
                bf16x4 vf = *(const bf16x4*)&vt[(dt * 16 + lr) * ASTR + ct * 16 + quad * 4];
                oacc[0][dt] = __builtin_amdgcn_mfma_f32_16x16x16bf16_1k(vf, pf0, oacc[0][dt], 0, 0, 0);
                oacc[1][dt] = __builtin_amdgcn_mfma_f32_16x16x16bf16_1k(vf, pf1, oacc[1][dt], 0, 0, 0);
            }
        }
    }

    // write O as plain fp16 for the proj GEMM
#pragma unroll
    for (int qs = 0; qs < 2; qs++) {
        const float inv = 1.0f / sacc[qs][0];
        const int row = b * SLEN + q0 + wq0 + qs * 16 + lr;
#pragma unroll
        for (int dt = 0; dt < 4; dt++) {
            f16x4 h4;
#pragma unroll
            for (int r = 0; r < 4; r++)
                h4[r] = (_Float16)(oacc[qs][dt][r] * inv);
            int col = h * HDIM + dt * 16 + quad * 4;
            *(f16x4*)&attn[(size_t)row * DMODEL + col] = h4;
        }
    }
}

extern "C" void kernel_launch(void* const* d_in, const int* in_sizes, int n_in,
                              void* d_out, int out_size, void* d_ws, size_t ws_size,
                              hipStream_t stream) {
    (void)in_sizes; (void)n_in; (void)out_size; (void)ws_size;
    const float* x     = (const float*)d_in[0];
    const float* Wqkv  = (const float*)d_in[1];
    const float* bqkv  = (const float*)d_in[2];
    const float* Wproj = (const float*)d_in[3];
    const float* bproj = (const float*)d_in[4];
    float* out = (float*)d_out;

    // workspace layout (2-byte units), peak ~58.6 MB
    short* qkv = (short*)d_ws;                               // 4096*3072 bf16
    _Float16* xf = (_Float16*)(qkv + (size_t)MROWS * 3 * DMODEL);  // 4096*1024 f16
    _Float16* wq = xf + (size_t)MROWS * DMODEL;              // 3072*1024 f16 (W_qkv^T)
    _Float16* wp = wq + (size_t)3 * DMODEL * DMODEL;         // 1024*1024 f16 (W_proj^T)
    short* vT = (short*)(wp + (size_t)DMODEL * DMODEL);      // 4096*1024 bf16
    _Float16* attnb = (_Float16*)(vT + (size_t)MROWS * DMODEL); // 4096*1024 f16

    // prep: cast x to fp16; transpose weights to fp16
    cast_f16<<<dim3(MROWS * DMODEL / 4 / 256), 256, 0, stream>>>(x, xf, MROWS * DMODEL / 4);
    transpose_f16<<<dim3(3 * DMODEL / 64, DMODEL / 64), 256, 0, stream>>>(Wqkv, wq, DMODEL, 3 * DMODEL);
    transpose_f16<<<dim3(DMODEL / 64, DMODEL / 64), 256, 0, stream>>>(Wproj, wp, DMODEL, DMODEL);

    // 1) qkv(bf16) = x @ W_qkv + b_qkv   (plain fp16 MFMA)
    gemm_f16<1><<<dim3(3 * DMODEL / 128, MROWS / 128), 256, 0, stream>>>(
        xf, wq, bqkv, (void*)qkv, MROWS, 3 * DMODEL, DMODEL);

    // 1b) transpose V section -> vT[b][h][d][s]
    transpose_v<<<dim3(BATCH * NHEAD * (SLEN / 64)), 256, 0, stream>>>(qkv, vT);

    // 2) fused attention: bf16 qkv + vT -> attn (fp16); 128 q-rows/block
    attn_mfma<<<dim3(BATCH * NHEAD * (SLEN / 128)), 256, 0, stream>>>(qkv, vT, attnb);

    // 3) out(fp32) = attn @ W_proj + b_proj   (plain fp16 MFMA)
    gemm_f16<0><<<dim3(DMODEL / 128, MROWS / 128), 256, 0, stream>>>(
        attnb, wp, bproj, (void*)out, MROWS, DMODEL, DMODEL);
}